// Round 6
// baseline (3286.762 us; speedup 1.0000x reference)
//
#include <hip/hip_runtime.h>

constexpr int kN = 4096;
constexpr int kDim = 66;   // U + IN
constexpr int kU = 64;
constexpr float kAlpha = 0.2f;
constexpr float kSlope = 0.01f;
constexpr float kLog2e = 1.44269504f;

typedef _Float16 half8 __attribute__((ext_vector_type(8)));
typedef float floatx4 __attribute__((ext_vector_type(4)));

// ---- workspace layout (bytes); all sizes 256-aligned ----
constexpr size_t oPacked = 256;                                  // u32[64]: bar state + fmax keys live in [0,256)
constexpr size_t oX1   = oPacked + (size_t)kN * 64 * 8;          // f16 [kN][96]
constexpr size_t oX2   = oX1 + (size_t)kN * 96 * 2;              // f16 [kN][96]
constexpr size_t oHt   = oX2 + (size_t)kN * 96 * 2;              // f16 [4][68][kN]
constexpr size_t oHto  = oHt + (size_t)4 * 68 * kN * 2;          // f16 [68][kN]
constexpr size_t oF1   = oHto + (size_t)68 * kN * 2;             // f32 [4][kN]
constexpr size_t oF2   = oF1 + (size_t)4 * kN * 4;
constexpr size_t oFo1  = oF2 + (size_t)4 * kN * 4;               // f32 [kN]
constexpr size_t oFo2  = oFo1 + (size_t)kN * 4;
constexpr size_t oU    = oFo2 + (size_t)kN * 4;                  // f32 [kN][64]
constexpr size_t oPacc = oU + (size_t)kN * 64 * 4;               // f16 [16][kN][72]
constexpr size_t oB1t  = oPacc + (size_t)16 * kN * 72 * 2;       // f16 [4][80][96]
constexpr size_t oB1t2 = oB1t + (size_t)4 * 80 * 96 * 2;
constexpr size_t oB2t  = oB1t2 + (size_t)4 * 80 * 96 * 2;        // f16 [80][288]
constexpr size_t oB2t2 = oB2t + (size_t)80 * 288 * 2;
constexpr size_t oBgt  = oB2t2 + (size_t)80 * 288 * 2;           // f16 [128][96]
constexpr size_t oBft  = oBgt + (size_t)128 * 96 * 2;            // f16 [64][96]

__device__ inline unsigned int fkey(float f){
  unsigned int u = __float_as_uint(f);
  return (u & 0x80000000u) ? ~u : (u | 0x80000000u);
}
__device__ inline float funkey(unsigned int k){
  unsigned int u = (k & 0x80000000u) ? (k ^ 0x80000000u) : ~k;
  return __uint_as_float(u);
}

// ---- two-level grid barrier: bar[0..31]=group counters, bar[32]=root, bar[33]=generation ----
__device__ __forceinline__ void gbar(unsigned* bar){
  __syncthreads();
  if (threadIdx.x == 0){
    unsigned g = __hip_atomic_load(&bar[33], __ATOMIC_ACQUIRE, __HIP_MEMORY_SCOPE_AGENT);
    __threadfence();
    unsigned a = __hip_atomic_fetch_add(&bar[blockIdx.x >> 5], 1u, __ATOMIC_ACQ_REL, __HIP_MEMORY_SCOPE_AGENT);
    if (a == 31u){
      unsigned r = __hip_atomic_fetch_add(&bar[32], 1u, __ATOMIC_ACQ_REL, __HIP_MEMORY_SCOPE_AGENT);
      if (r == 31u){
        for (int z = 0; z < 32; z++)
          __hip_atomic_store(&bar[z], 0u, __ATOMIC_RELAXED, __HIP_MEMORY_SCOPE_AGENT);
        __hip_atomic_store(&bar[32], 0u, __ATOMIC_RELAXED, __HIP_MEMORY_SCOPE_AGENT);
        __hip_atomic_fetch_add(&bar[33], 1u, __ATOMIC_RELEASE, __HIP_MEMORY_SCOPE_AGENT);
      } else {
        while (__hip_atomic_load(&bar[33], __ATOMIC_ACQUIRE, __HIP_MEMORY_SCOPE_AGENT) == g)
          __builtin_amdgcn_s_sleep(2);
      }
    } else {
      while (__hip_atomic_load(&bar[33], __ATOMIC_ACQUIRE, __HIP_MEMORY_SCOPE_AGENT) == g)
        __builtin_amdgcn_s_sleep(2);
    }
    __threadfence();
  }
  __syncthreads();
}

// ---- generic MFMA GEMM core: Arow = lane's A row base ----
template<int KSTEPS, int NT>
__device__ __forceinline__ void gemmN(const _Float16* __restrict__ Arow,
                                      const _Float16* __restrict__ Bt, floatx4* acc){
  const int lane = threadIdx.x & 63, q = lane >> 4, n = lane & 15;
  #pragma unroll
  for (int v = 0; v < NT; v++) acc[v] = (floatx4){0.f, 0.f, 0.f, 0.f};
  #pragma unroll
  for (int ks = 0; ks < KSTEPS; ks++){
    half8 af = *(const half8*)&Arow[ks * 32 + q * 8];
    #pragma unroll
    for (int nt = 0; nt < NT; nt++){
      half8 bf = *(const half8*)&Bt[(size_t)(nt * 16 + n) * (KSTEPS * 32) + ks * 32 + q * 8];
      acc[nt] = __builtin_amdgcn_mfma_f32_16x16x32_f16(af, bf, acc[nt], 0, 0, 0);
    }
  }
}

// ---- EPI0: store Ht (fp16 transposed + ones row 66 + zero row 67), f1/f2 (xlog2e), fmax ----
__device__ __forceinline__ void epi0(floatx4* acc, int i0, _Float16* __restrict__ Htc,
                                     float* __restrict__ f1c, float* __restrict__ f2c,
                                     unsigned* __restrict__ fmaxslot){
  const int t = threadIdx.x, w = t >> 6, lane = t & 63, q = lane >> 4, n = lane & 15;
  const int ib = i0 + w * 16 + q * 4;
  float lm = -3e38f;
  #pragma unroll
  for (int nt = 0; nt < 5; nt++){
    int c = nt * 16 + n;
    if (c < kDim){
      union { _Float16 h[4]; uint2 v; } pk;
      pk.h[0] = (_Float16)acc[nt][0]; pk.h[1] = (_Float16)acc[nt][1];
      pk.h[2] = (_Float16)acc[nt][2]; pk.h[3] = (_Float16)acc[nt][3];
      *(uint2*)&Htc[(size_t)c * kN + ib] = pk.v;
    } else if (c == 66){
      float4 fv; fv.x = acc[nt][0] * kLog2e; fv.y = acc[nt][1] * kLog2e;
      fv.z = acc[nt][2] * kLog2e; fv.w = acc[nt][3] * kLog2e;
      *(float4*)&f1c[ib] = fv;
      *(uint2*)&Htc[(size_t)66 * kN + ib] = make_uint2(0x3C003C00u, 0x3C003C00u);
    } else if (c == 67){
      float4 fv; fv.x = acc[nt][0] * kLog2e; fv.y = acc[nt][1] * kLog2e;
      fv.z = acc[nt][2] * kLog2e; fv.w = acc[nt][3] * kLog2e;
      *(float4*)&f2c[ib] = fv;
      lm = fmaxf(fmaxf(fv.x, fv.y), fmaxf(fv.z, fv.w));
      *(uint2*)&Htc[(size_t)67 * kN + ib] = make_uint2(0u, 0u);
    }
  }
  lm = fmaxf(lm, __shfl_xor(lm, 16));
  lm = fmaxf(lm, __shfl_xor(lm, 32));
  if (lane == 3) atomicMax(fmaxslot, fkey(lm));
}

// ---- attention stage: factorized softmax p = max(A1*B1j, A2*B2j), MFMA accumulate ----
template<int NCH>
__device__ __forceinline__ void attn_stage(
    const _Float16* __restrict__ Hg, const float* __restrict__ f1c, const float* __restrict__ f2c,
    unsigned fmaxkey, const unsigned long long* __restrict__ packedp,
    _Float16* __restrict__ paccout, int i0, int jbase,
    _Float16* __restrict__ HtL, _Float16* __restrict__ B1h, _Float16* __restrict__ B2h)
{
  typedef _Float16 half2t __attribute__((ext_vector_type(2)));
  const int t = threadIdx.x, w = t >> 6, lane = t & 63, q = lane >> 4, n = lane & 15;
  const int i = i0 + w * 16 + n;
  const float f1v = f1c[i];
  const float fmx = funkey(fmaxkey);
  const float t0 = f1v + fmx;
  const float S = fmaxf(t0, kAlpha * t0);
  const float A1f = __builtin_amdgcn_exp2f(t0 - S);
  const float A2f = __builtin_amdgcn_exp2f(kAlpha * t0 - S);
  const half2t a1p = { (_Float16)A1f, (_Float16)A1f };
  const half2t a2p = { (_Float16)A2f, (_Float16)A2f };

  for (int z = t; z < 12 * 136; z += 256) HtL[68 * 136 + z] = (_Float16)0.f;

  floatx4 acc[5];
  #pragma unroll
  for (int v = 0; v < 5; v++) acc[v] = (floatx4){0.f, 0.f, 0.f, 0.f};

  const unsigned long long* prow = packedp + (size_t)i * 64;
  for (int ch = 0; ch < NCH; ch++){
    const int j0 = jbase + ch * 128;
    __syncthreads();
    for (int z = t; z < 68 * 16; z += 256){
      int row = z >> 4, c16 = z & 15;
      *(uint4*)&HtL[row * 136 + c16 * 8] = *(const uint4*)&Hg[(size_t)row * kN + j0 + c16 * 8];
    }
    if (t < 128){
      float v = f2c[j0 + t] - fmx;
      B1h[t] = (_Float16)__builtin_amdgcn_exp2f(v);
      B2h[t] = (_Float16)__builtin_amdgcn_exp2f(kAlpha * v);
    }
    __syncthreads();
    unsigned long long w0 = prow[(j0 >> 6)];
    unsigned long long w1 = prow[(j0 >> 6) + 1];
    #pragma unroll
    for (int ks = 0; ks < 4; ks++){
      unsigned long long wsel = (ks < 2) ? w0 : w1;
      unsigned int bits = (unsigned int)((wsel >> ((ks & 1) * 32 + q * 8)) & 0xffull);
      union { uint4 v; unsigned int u[4]; } b1v, b2v;
      b1v.v = *(const uint4*)&B1h[ks * 32 + q * 8];
      b2v.v = *(const uint4*)&B2h[ks * 32 + q * 8];
      union { half8 s; unsigned int u[4]; } af;
      #pragma unroll
      for (int e = 0; e < 4; e++){
        half2t x1 = __builtin_bit_cast(half2t, b1v.u[e]);
        half2t x2 = __builtin_bit_cast(half2t, b2v.u[e]);
        half2t m1 = x1 * a1p;
        half2t m2 = x2 * a2p;
        half2t pm = __builtin_elementwise_max(m1, m2);
        unsigned int mm = (((bits >> (2 * e)) & 1u) ? 0x0000FFFFu : 0u)
                        | (((bits >> (2 * e + 1)) & 1u) ? 0xFFFF0000u : 0u);
        af.u[e] = __builtin_bit_cast(unsigned int, pm) & mm;
      }
      #pragma unroll
      for (int nt = 0; nt < 5; nt++){
        const half8 bf = *(const half8*)&HtL[(nt * 16 + n) * 136 + ks * 32 + q * 8];
        acc[nt] = __builtin_amdgcn_mfma_f32_16x16x32_f16(af.s, bf, acc[nt], 0, 0, 0);
      }
    }
  }
  _Float16* pw = paccout + (size_t)(i0 + w * 16) * 72;
  #pragma unroll
  for (int nt = 0; nt < 5; nt++){
    if (nt < 4 || n < 4){
      #pragma unroll
      for (int r = 0; r < 4; r++)
        pw[(q * 4 + r) * 72 + nt * 16 + n] = (_Float16)acc[nt][r];
    }
  }
}

// ---- combine 4 head j-split partials into LDS hcat, then out-layer GEMM (K=288) ----
__device__ __forceinline__ void combineH_gemmO(
    const _Float16* __restrict__ pacc, const _Float16* __restrict__ B2tc,
    _Float16* __restrict__ Htoc, float* __restrict__ fo1c, float* __restrict__ fo2c,
    unsigned* __restrict__ fmaxslot, int i0, _Float16* __restrict__ hcatL)
{
  const int t = threadIdx.x;
  {
    const int mm = t >> 6, row = t & 63;
    const _Float16* pb = pacc + ((size_t)(mm * 4) * kN + (i0 + row)) * 72;
    constexpr size_t jstep = (size_t)kN * 72;
    float l = 0.f;
    #pragma unroll
    for (int s = 0; s < 4; s++) l += (float)pb[s * jstep + 66];
    float inv = 1.f / l;
    _Float16* hr = hcatL + row * 296 + mm * 66;
    #pragma unroll
    for (int c8 = 0; c8 < 9; c8++){
      float sv[8] = {0.f,0.f,0.f,0.f,0.f,0.f,0.f,0.f};
      #pragma unroll
      for (int s = 0; s < 4; s++){
        half8 hv = *(const half8*)&pb[s * jstep + c8 * 8];
        #pragma unroll
        for (int e = 0; e < 8; e++) sv[e] += (float)hv[e];
      }
      #pragma unroll
      for (int e = 0; e < 8; e++){
        int c = c8 * 8 + e;
        if (c < kDim){
          float vv = sv[e] * inv;
          vv = fmaxf(vv, kSlope * vv);
          hr[c] = (_Float16)vv;
        }
      }
    }
  }
  for (int z = t; z < 64 * 32; z += 256)
    hcatL[(z >> 5) * 296 + 264 + (z & 31)] = (_Float16)0.f;
  __syncthreads();
  const int w = t >> 6, lane = t & 63, n = lane & 15;
  floatx4 acc[5];
  gemmN<9, 5>(hcatL + (w * 16 + n) * 296, B2tc, acc);
  epi0(acc, i0, Htoc, fo1c, fo2c, fmaxslot);
}

// ---- combine 16 out j-split partials into LDS, then gate(EPI=1)/final(EPI=2) GEMM (K=96) ----
template<int EPI>
__device__ __forceinline__ void combineO_gemm(
    const _Float16* __restrict__ pacc, const _Float16* __restrict__ Btc,
    float* __restrict__ uv, const float* __restrict__ hxp,
    _Float16* __restrict__ x2bp, float* __restrict__ outp,
    int i0, _Float16* __restrict__ gbL)
{
  const int t = threadIdx.x;
  {
    const int row = t >> 2, cg = t & 3;
    const _Float16* pb = pacc + (size_t)(i0 + row) * 72;
    constexpr size_t jstep = (size_t)kN * 72;
    float l = 0.f;
    #pragma unroll
    for (int s = 0; s < 16; s++) l += (float)pb[s * jstep + 66];
    float inv = 1.f / l;
    _Float16* gr = gbL + row * 104;
    for (int cc = 0; cc < 17; cc++){
      int c = cg * 17 + cc;
      if (c < kDim){
        float vv = 0.f;
        #pragma unroll
        for (int s = 0; s < 16; s++) vv += (float)pb[s * jstep + c];
        vv *= inv; vv = fmaxf(vv, kSlope * vv);
        gr[c] = (_Float16)vv;
      } else if (c == 66) gr[66] = (_Float16)1.f;
      else if (c == 67) gr[67] = (_Float16)0.f;
    }
    #pragma unroll
    for (int e = 0; e < 9; e++) gr[68 + cg * 9 + e] = (_Float16)0.f;
  }
  __syncthreads();
  const int w = t >> 6, lane = t & 63, q = lane >> 4, n = lane & 15;
  const int ib = i0 + w * 16 + q * 4;
  if constexpr (EPI == 1){
    floatx4 acc[8];
    gemmN<3, 8>(gbL + (w * 16 + n) * 104, Btc, acc);
    #pragma unroll
    for (int nt = 0; nt < 8; nt++){
      int c = nt * 16 + n;
      #pragma unroll
      for (int r = 0; r < 4; r++){
        float v = 1.f / (1.f + __expf(-acc[nt][r]));
        if (c < 64) x2bp[(size_t)(ib + r) * 96 + 2 + c] = (_Float16)(v * hxp[(size_t)(ib + r) * kU + c]);
        else        uv[(size_t)(ib + r) * kU + (c - 64)] = v;
      }
    }
  } else {
    floatx4 acc[4];
    gemmN<3, 4>(gbL + (w * 16 + n) * 104, Btc, acc);
    #pragma unroll
    for (int nt = 0; nt < 4; nt++){
      int c = nt * 16 + n;
      #pragma unroll
      for (int r = 0; r < 4; r++){
        float cc2 = tanhf(acc[nt][r]);
        float u2 = uv[(size_t)(ib + r) * kU + c];
        outp[(size_t)(ib + r) * kU + c] = u2 * hxp[(size_t)(ib + r) * kU + c] + (1.f - u2) * cc2;
      }
    }
  }
}

__global__ void init_k(unsigned* __restrict__ bar){
  if (threadIdx.x < 64) bar[threadIdx.x] = 0u;  // barrier state + fmax keys
}

__global__ __launch_bounds__(256, 4) void mega_k(
    const int* __restrict__ adj, const float* __restrict__ in2, const float* __restrict__ hx,
    const float* __restrict__ m1W, const float* __restrict__ m1a1, const float* __restrict__ m1a2,
    const float* __restrict__ m1Wo, const float* __restrict__ m1ao1, const float* __restrict__ m1ao2,
    const float* __restrict__ m2W, const float* __restrict__ m2a1, const float* __restrict__ m2a2,
    const float* __restrict__ m2Wo, const float* __restrict__ m2ao1, const float* __restrict__ m2ao2,
    const float* __restrict__ g1W, const float* __restrict__ g1b,
    const float* __restrict__ g2W, const float* __restrict__ g2b,
    float* __restrict__ out, unsigned char* __restrict__ ws)
{
  __shared__ __align__(16) unsigned char smem[38400];
  unsigned* bar = (unsigned*)ws;
  unsigned* fmaxb = bar + 48;
  unsigned long long* packed = (unsigned long long*)(ws + oPacked);
  _Float16* x1b  = (_Float16*)(ws + oX1);
  _Float16* x2b  = (_Float16*)(ws + oX2);
  _Float16* Ht   = (_Float16*)(ws + oHt);
  _Float16* Hto  = (_Float16*)(ws + oHto);
  float* f1  = (float*)(ws + oF1);
  float* f2  = (float*)(ws + oF2);
  float* fo1 = (float*)(ws + oFo1);
  float* fo2 = (float*)(ws + oFo2);
  float* u   = (float*)(ws + oU);
  _Float16* pacc = (_Float16*)(ws + oPacc);
  _Float16* B1t  = (_Float16*)(ws + oB1t);
  _Float16* B1t2 = (_Float16*)(ws + oB1t2);
  _Float16* B2t  = (_Float16*)(ws + oB2t);
  _Float16* B2t2 = (_Float16*)(ws + oB2t2);
  _Float16* Bgt  = (_Float16*)(ws + oBgt);
  _Float16* Bft  = (_Float16*)(ws + oBft);
  _Float16* HtL = (_Float16*)smem;
  _Float16* B1h = (_Float16*)(smem + 21760);
  _Float16* B2h = (_Float16*)(smem + 22016);

  const int bid = blockIdx.x, t = threadIdx.x;

  // ================= stage 0: setup =================
  for (int c = 0; c < 64; c++){
    int gid = bid * 16384 + c * 256 + t;
    unsigned long long mmask = __ballot(adj[gid] != 0);
    if ((t & 63) == 0) packed[gid >> 6] = mmask;
  }
  {
    int i = bid * 4 + (t >> 6), c = t & 63;
    x1b[(size_t)i * 96 + 2 + c] = (_Float16)hx[(size_t)i * kU + c];
    if (c < 2){
      _Float16 xv = (_Float16)in2[i * 2 + c];
      x1b[(size_t)i * 96 + c] = xv;
      x2b[(size_t)i * 96 + c] = xv;
    }
    if (c < 30){
      x1b[(size_t)i * 96 + 66 + c] = (_Float16)0.f;
      x2b[(size_t)i * 96 + 66 + c] = (_Float16)0.f;
    }
  }
  if (bid < 12){
    int b = bid;
    if (b < 8){
      int mh = b & 3;
      const float* W  = (b < 4 ? m1W  : m2W)  + (size_t)mh * kDim * kDim;
      const float* a1 = (b < 4 ? m1a1 : m2a1) + mh * kDim;
      const float* a2 = (b < 4 ? m1a2 : m2a2) + mh * kDim;
      _Float16* Bo = (b < 4 ? B1t : B1t2) + (size_t)mh * 80 * 96;
      float* Ws = (float*)smem;
      float* wa1s = Ws + kDim * kDim;
      float* wa2s = wa1s + kDim;
      for (int z = t; z < kDim * kDim; z += 256) Ws[z] = W[z];
      __syncthreads();
      if (t < kDim){
        float s1 = 0.f, s2 = 0.f;
        for (int d = 0; d < kDim; d++){ float wv = Ws[t * kDim + d]; s1 += wv * a1[d]; s2 += wv * a2[d]; }
        wa1s[t] = s1; wa2s[t] = s2;
      }
      __syncthreads();
      for (int z = t; z < 80 * 96; z += 256){
        int nn = z / 96, k = z % 96;
        float val = 0.f;
        if (k < kDim){
          if (nn < kDim) val = Ws[k * kDim + nn];
          else if (nn == 66) val = wa1s[k];
          else if (nn == 67) val = wa2s[k];
        }
        Bo[z] = (_Float16)val;
      }
    } else if (b < 10){
      const float* Wo  = (b == 8 ? m1Wo  : m2Wo);
      const float* ao1 = (b == 8 ? m1ao1 : m2ao1);
      const float* ao2 = (b == 8 ? m1ao2 : m2ao2);
      _Float16* Bo = (b == 8 ? B2t : B2t2);
      float* wo1s = (float*)smem;
      float* wo2s = wo1s + 264;
      for (int k = t; k < 264; k += 256){
        float s1 = 0.f, s2 = 0.f;
        for (int d = 0; d < kDim; d++){ float wv = Wo[(size_t)k * kDim + d]; s1 += wv * ao1[d]; s2 += wv * ao2[d]; }
        wo1s[k] = s1; wo2s[k] = s2;
      }
      __syncthreads();
      for (int z = t; z < 80 * 288; z += 256){
        int nn = z / 288, k = z % 288;
        float val = 0.f;
        if (k < 264){
          if (nn < kDim) val = Wo[(size_t)k * kDim + nn];
          else if (nn == 66) val = wo1s[k];
          else if (nn == 67) val = wo2s[k];
        }
        Bo[z] = (_Float16)val;
      }
    } else if (b == 10){
      for (int z = t; z < 128 * 96; z += 256){
        int nn = z / 96, k = z % 96;
        float val = 0.f;
        if (k < kDim) val = g1W[k * 128 + nn];
        else if (k == 66) val = g1b[nn];
        Bgt[z] = (_Float16)val;
      }
    } else {
      for (int z = t; z < 64 * 96; z += 256){
        int nn = z / 96, k = z % 96;
        float val = 0.f;
        if (k < kDim) val = g2W[k * 64 + nn];
        else if (k == 66) val = g2b[nn];
        Bft[z] = (_Float16)val;
      }
    }
  }
  gbar(bar);

  // ================= subnet 1 =================
  if (bid < 256){
    int mh = bid >> 6, i0 = (bid & 63) * 64;
    const int w = t >> 6, n = t & 15;
    floatx4 acc[5];
    gemmN<3, 5>(x1b + (size_t)(i0 + w * 16 + n) * 96, B1t + (size_t)mh * 80 * 96, acc);
    epi0(acc, i0, Ht + (size_t)mh * 68 * kN, f1 + (size_t)mh * kN, f2 + (size_t)mh * kN, fmaxb + mh);
  }
  gbar(bar);
  {
    int i0 = (bid & 63) * 64, mh = (bid >> 6) & 3, js = bid >> 8;
    attn_stage<8>(Ht + (size_t)mh * 68 * kN, f1 + (size_t)mh * kN, f2 + (size_t)mh * kN,
                  fmaxb[mh], packed, pacc + (size_t)(mh * 4 + js) * kN * 72, i0, js * 1024,
                  HtL, B1h, B2h);
  }
  gbar(bar);
  if (bid < 64)
    combineH_gemmO(pacc, B2t, Hto, fo1, fo2, fmaxb + 4, bid * 64, (_Float16*)smem);
  gbar(bar);
  {
    int i0 = (bid & 63) * 64, js = bid >> 6;
    attn_stage<2>(Hto, fo1, fo2, fmaxb[4], packed, pacc + (size_t)js * kN * 72, i0, js * 256,
                  HtL, B1h, B2h);
  }
  gbar(bar);
  if (bid < 64)
    combineO_gemm<1>(pacc, Bgt, u, hx, x2b, nullptr, bid * 64, (_Float16*)smem);
  gbar(bar);

  // ================= subnet 2 =================
  if (bid < 256){
    int mh = bid >> 6, i0 = (bid & 63) * 64;
    const int w = t >> 6, n = t & 15;
    floatx4 acc[5];
    gemmN<3, 5>(x2b + (size_t)(i0 + w * 16 + n) * 96, B1t2 + (size_t)mh * 80 * 96, acc);
    epi0(acc, i0, Ht + (size_t)mh * 68 * kN, f1 + (size_t)mh * kN, f2 + (size_t)mh * kN, fmaxb + 5 + mh);
  }
  gbar(bar);
  {
    int i0 = (bid & 63) * 64, mh = (bid >> 6) & 3, js = bid >> 8;
    attn_stage<8>(Ht + (size_t)mh * 68 * kN, f1 + (size_t)mh * kN, f2 + (size_t)mh * kN,
                  fmaxb[5 + mh], packed, pacc + (size_t)(mh * 4 + js) * kN * 72, i0, js * 1024,
                  HtL, B1h, B2h);
  }
  gbar(bar);
  if (bid < 64)
    combineH_gemmO(pacc, B2t2, Hto, fo1, fo2, fmaxb + 9, bid * 64, (_Float16*)smem);
  gbar(bar);
  {
    int i0 = (bid & 63) * 64, js = bid >> 6;
    attn_stage<2>(Hto, fo1, fo2, fmaxb[9], packed, pacc + (size_t)js * kN * 72, i0, js * 256,
                  HtL, B1h, B2h);
  }
  gbar(bar);
  if (bid < 64)
    combineO_gemm<2>(pacc, Bft, u, hx, nullptr, out, bid * 64, (_Float16*)smem);
}

extern "C" void kernel_launch(void* const* d_in, const int* in_sizes, int n_in,
                              void* d_out, int out_size, void* d_ws, size_t ws_size,
                              hipStream_t stream){
  const float* inputs  = (const float*)d_in[0];
  const float* hx      = (const float*)d_in[1];
  const int*   adj     = (const int*)d_in[2];
  const float* m1_W    = (const float*)d_in[3];
  const float* m1_a1   = (const float*)d_in[4];
  const float* m1_a2   = (const float*)d_in[5];
  const float* m1_Wout = (const float*)d_in[6];
  const float* m1_ao1  = (const float*)d_in[7];
  const float* m1_ao2  = (const float*)d_in[8];
  const float* m2_W    = (const float*)d_in[9];
  const float* m2_a1   = (const float*)d_in[10];
  const float* m2_a2   = (const float*)d_in[11];
  const float* m2_Wout = (const float*)d_in[12];
  const float* m2_ao1  = (const float*)d_in[13];
  const float* m2_ao2  = (const float*)d_in[14];
  const float* g1_W    = (const float*)d_in[15];
  const float* g1_b    = (const float*)d_in[16];
  const float* g2_W    = (const float*)d_in[17];
  const float* g2_b    = (const float*)d_in[18];
  float* out = (float*)d_out;
  unsigned char* ws = (unsigned char*)d_ws;
  (void)in_sizes; (void)n_in; (void)out_size; (void)ws_size;

  init_k<<<1, 64, 0, stream>>>((unsigned*)ws);
  mega_k<<<1024, 256, 0, stream>>>(adj, inputs, hx,
      m1_W, m1_a1, m1_a2, m1_Wout, m1_ao1, m1_ao2,
      m2_W, m2_a1, m2_a2, m2_Wout, m2_ao1, m2_ao2,
      g1_W, g1_b, g2_W, g2_b, out, ws);
}

// Round 7
// 322.750 us; speedup vs baseline: 10.1836x; 10.1836x over previous
//
#include <hip/hip_runtime.h>

constexpr int kN = 4096;
constexpr int kDim = 66;   // U + IN
constexpr int kU = 64;
constexpr float kAlpha = 0.2f;
constexpr float kSlope = 0.01f;
constexpr float kLog2e = 1.44269504f;

typedef _Float16 half8 __attribute__((ext_vector_type(8)));
typedef _Float16 half2t __attribute__((ext_vector_type(2)));
typedef float floatx4 __attribute__((ext_vector_type(4)));

__device__ inline unsigned int fkey(float f){ // monotone float->uint key for atomicMax
  unsigned int u = __float_as_uint(f);
  return (u & 0x80000000u) ? ~u : (u | 0x80000000u);
}
__device__ inline float funkey(unsigned int k){
  unsigned int u = (k & 0x80000000u) ? (k ^ 0x80000000u) : ~k;
  return __uint_as_float(u);
}

// ---------- merged setup: pack adjacency + build fp16 x1/x2 + all B matrices + fmax init ----------
__global__ void setup_k(const int* __restrict__ adj, unsigned long long* __restrict__ packed,
                        const float* __restrict__ in2, const float* __restrict__ hx,
                        _Float16* __restrict__ x1b, _Float16* __restrict__ x2b,
                        const float* __restrict__ m1W, const float* __restrict__ m1a1, const float* __restrict__ m1a2,
                        const float* __restrict__ m1Wo, const float* __restrict__ m1ao1, const float* __restrict__ m1ao2,
                        const float* __restrict__ m2W, const float* __restrict__ m2a1, const float* __restrict__ m2a2,
                        const float* __restrict__ m2Wo, const float* __restrict__ m2ao1, const float* __restrict__ m2ao2,
                        const float* __restrict__ g1W, const float* __restrict__ g1b,
                        const float* __restrict__ g2W, const float* __restrict__ g2b,
                        _Float16* __restrict__ B1t, _Float16* __restrict__ B1t2,
                        _Float16* __restrict__ B2t, _Float16* __restrict__ B2t2,
                        _Float16* __restrict__ Bgt, _Float16* __restrict__ Bft,
                        unsigned int* __restrict__ fmaxbuf){
  int bb = blockIdx.x, t = threadIdx.x;
  if (bb < 16384){
    int gid = bb * 256 + t;
    unsigned long long m = __ballot(adj[gid] != 0);
    if ((t & 63) == 0) packed[gid >> 6] = m;
    return;
  }
  if (bb < 16384 + 1024){
    int i = (bb - 16384) * 4 + (t >> 6);
    int c = t & 63;
    x1b[(size_t)i * 96 + 2 + c] = (_Float16)hx[(size_t)i * kU + c];
    if (c < 2){
      _Float16 xv = (_Float16)in2[i * 2 + c];
      x1b[(size_t)i * 96 + c] = xv;
      x2b[(size_t)i * 96 + c] = xv;
    }
    if (c < 30){ // zero pad cols 66..95 (ws is poisoned)
      x1b[(size_t)i * 96 + 66 + c] = (_Float16)0.f;
      x2b[(size_t)i * 96 + 66 + c] = (_Float16)0.f;
    }
    return;
  }
  int b = bb - (16384 + 1024);
  if (b < 8){
    int m = b & 3;
    const float* W  = (b < 4 ? m1W  : m2W)  + (size_t)m * kDim * kDim;
    const float* a1 = (b < 4 ? m1a1 : m2a1) + m * kDim;
    const float* a2 = (b < 4 ? m1a2 : m2a2) + m * kDim;
    _Float16* Bo = (b < 4 ? B1t : B1t2) + (size_t)m * 80 * 96;
    __shared__ float Ws[kDim * kDim];
    __shared__ float wa1s[kDim], wa2s[kDim];
    for (int z = t; z < kDim * kDim; z += 256) Ws[z] = W[z];
    __syncthreads();
    if (t < kDim){
      float s1 = 0.f, s2 = 0.f;
      for (int d = 0; d < kDim; d++){ float wv = Ws[t * kDim + d]; s1 += wv * a1[d]; s2 += wv * a2[d]; }
      wa1s[t] = s1; wa2s[t] = s2;
    }
    __syncthreads();
    for (int z = t; z < 80 * 96; z += 256){
      int nn = z / 96, k = z % 96;
      float val = 0.f;
      if (k < kDim){
        if (nn < kDim) val = Ws[k * kDim + nn];
        else if (nn == 66) val = wa1s[k];
        else if (nn == 67) val = wa2s[k];
      }
      Bo[z] = (_Float16)val;
    }
  } else if (b < 10){
    const float* Wo  = (b == 8 ? m1Wo  : m2Wo);
    const float* ao1 = (b == 8 ? m1ao1 : m2ao1);
    const float* ao2 = (b == 8 ? m1ao2 : m2ao2);
    _Float16* Bo = (b == 8 ? B2t : B2t2);
    __shared__ float wo1s[264], wo2s[264];
    for (int k = t; k < 264; k += 256){
      float s1 = 0.f, s2 = 0.f;
      for (int d = 0; d < kDim; d++){ float wv = Wo[(size_t)k * kDim + d]; s1 += wv * ao1[d]; s2 += wv * ao2[d]; }
      wo1s[k] = s1; wo2s[k] = s2;
    }
    __syncthreads();
    for (int z = t; z < 80 * 288; z += 256){
      int nn = z / 288, k = z % 288;
      float val = 0.f;
      if (k < 264){
        if (nn < kDim) val = Wo[(size_t)k * kDim + nn];
        else if (nn == 66) val = wo1s[k];
        else if (nn == 67) val = wo2s[k];
      }
      Bo[z] = (_Float16)val;
    }
  } else if (b == 10){
    for (int z = t; z < 128 * 96; z += 256){
      int nn = z / 96, k = z % 96;
      float val = 0.f;
      if (k < kDim) val = g1W[k * 128 + nn];
      else if (k == 66) val = g1b[nn];
      Bgt[z] = (_Float16)val;
    }
  } else {
    if (t < 16) fmaxbuf[t] = 0u; // init max-key slots
    for (int z = t; z < 64 * 96; z += 256){
      int nn = z / 96, k = z % 96;
      float val = 0.f;
      if (k < kDim) val = g2W[k * 64 + nn];
      else if (k == 66) val = g2b[nn];
      Bft[z] = (_Float16)val;
    }
  }
}

// ---- generic MFMA GEMM core: Arow = lane's A row base ----
template<int KSTEPS, int NT>
__device__ __forceinline__ void gemmN(const _Float16* __restrict__ Arow,
                                      const _Float16* __restrict__ Bt, floatx4* acc){
  const int lane = threadIdx.x & 63, q = lane >> 4, n = lane & 15;
  #pragma unroll
  for (int v = 0; v < NT; v++) acc[v] = (floatx4){0.f, 0.f, 0.f, 0.f};
  #pragma unroll
  for (int ks = 0; ks < KSTEPS; ks++){
    half8 af = *(const half8*)&Arow[ks * 32 + q * 8];
    #pragma unroll
    for (int nt = 0; nt < NT; nt++){
      half8 bf = *(const half8*)&Bt[(size_t)(nt * 16 + n) * (KSTEPS * 32) + ks * 32 + q * 8];
      acc[nt] = __builtin_amdgcn_mfma_f32_16x16x32_f16(af, bf, acc[nt], 0, 0, 0);
    }
  }
}

// ---- EPI0: store Ht (fp16 transposed + ones row 66 + zero row 67), f1/f2 (xlog2e), fmax ----
__device__ __forceinline__ void epi0(floatx4* acc, int i0, _Float16* __restrict__ Htc,
                                     float* __restrict__ f1c, float* __restrict__ f2c,
                                     unsigned* __restrict__ fmaxslot){
  const int t = threadIdx.x, w = t >> 6, lane = t & 63, q = lane >> 4, n = lane & 15;
  const int ib = i0 + w * 16 + q * 4;
  float lm = -3e38f;
  #pragma unroll
  for (int nt = 0; nt < 5; nt++){
    int c = nt * 16 + n;
    if (c < kDim){
      union { _Float16 h[4]; uint2 v; } pk;
      pk.h[0] = (_Float16)acc[nt][0]; pk.h[1] = (_Float16)acc[nt][1];
      pk.h[2] = (_Float16)acc[nt][2]; pk.h[3] = (_Float16)acc[nt][3];
      *(uint2*)&Htc[(size_t)c * kN + ib] = pk.v;
    } else if (c == 66){
      float4 fv; fv.x = acc[nt][0] * kLog2e; fv.y = acc[nt][1] * kLog2e;
      fv.z = acc[nt][2] * kLog2e; fv.w = acc[nt][3] * kLog2e;
      *(float4*)&f1c[ib] = fv;
      *(uint2*)&Htc[(size_t)66 * kN + ib] = make_uint2(0x3C003C00u, 0x3C003C00u);
    } else if (c == 67){
      float4 fv; fv.x = acc[nt][0] * kLog2e; fv.y = acc[nt][1] * kLog2e;
      fv.z = acc[nt][2] * kLog2e; fv.w = acc[nt][3] * kLog2e;
      *(float4*)&f2c[ib] = fv;
      lm = fmaxf(fmaxf(fv.x, fv.y), fmaxf(fv.z, fv.w));
      *(uint2*)&Htc[(size_t)67 * kN + ib] = make_uint2(0u, 0u);
    }
  }
  lm = fmaxf(lm, __shfl_xor(lm, 16));
  lm = fmaxf(lm, __shfl_xor(lm, 32));
  if (lane == 3) atomicMax(fmaxslot, fkey(lm));
}

// ---------- head transform GEMM: Ht = (x@W | ones), f1, f2, fmax ----------
__global__ __launch_bounds__(256) void gemm_ht_k(
    const _Float16* __restrict__ A, const _Float16* __restrict__ Bt,
    _Float16* __restrict__ Ht, float* __restrict__ f1, float* __restrict__ f2,
    unsigned int* __restrict__ fmaxp)
{
  const int m = blockIdx.y;
  const int i0 = blockIdx.x * 64;
  const int w = threadIdx.x >> 6, n = threadIdx.x & 15;
  floatx4 acc[5];
  gemmN<3, 5>(A + (size_t)(i0 + w * 16 + n) * 96, Bt + (size_t)m * 80 * 96, acc);
  epi0(acc, i0, Ht + (size_t)m * 68 * kN, f1 + (size_t)m * kN, f2 + (size_t)m * kN, fmaxp + m);
}

// ---------- MFMA attention (fp16, factorized softmax weights), pacc stride 72 ----------
template<int JSPLIT>
__global__ __launch_bounds__(256, 4) void attn_mfma_k(
    const _Float16* __restrict__ Ht, const float* __restrict__ f1,
    const float* __restrict__ f2, const unsigned int* __restrict__ fmaxu,
    const unsigned long long* __restrict__ packed,
    _Float16* __restrict__ paccb)
{
  constexpr int JR = kN / JSPLIT;
  constexpr int NCH = JR / 128;
  const int m = blockIdx.y, js = blockIdx.z;
  const int i0 = blockIdx.x * 64;
  const int t = threadIdx.x;
  const int w = t >> 6, lane = t & 63, q = lane >> 4, n = lane & 15;
  const int i = i0 + w * 16 + n;
  const _Float16* Hg = Ht + (size_t)m * 68 * kN;
  const float* f2m = f2 + (size_t)m * kN;
  const float f1v = f1[(size_t)m * kN + i];
  const float fmx = funkey(fmaxu[m]);
  const float t0 = f1v + fmx;
  const float S = fmaxf(t0, kAlpha * t0);
  const float A1f = __builtin_amdgcn_exp2f(t0 - S);
  const float A2f = __builtin_amdgcn_exp2f(kAlpha * t0 - S);
  const half2t a1p = { (_Float16)A1f, (_Float16)A1f };
  const half2t a2p = { (_Float16)A2f, (_Float16)A2f };

  __shared__ __align__(16) _Float16 HtL[80 * 136];
  __shared__ __align__(16) _Float16 B1h[128], B2h[128];

  for (int z = t; z < 12 * 136; z += 256) HtL[68 * 136 + z] = (_Float16)0.f;

  floatx4 acc[5];
  #pragma unroll
  for (int v = 0; v < 5; v++) acc[v] = (floatx4){0.f, 0.f, 0.f, 0.f};

  const int jbase = js * JR;
  const unsigned long long* prow = packed + (size_t)i * 64;
  for (int ch = 0; ch < NCH; ch++){
    const int j0 = jbase + ch * 128;
    __syncthreads();
    for (int z = t; z < 68 * 16; z += 256){
      int row = z >> 4, c16 = z & 15;
      *(uint4*)&HtL[row * 136 + c16 * 8] = *(const uint4*)&Hg[(size_t)row * kN + j0 + c16 * 8];
    }
    if (t < 128){
      float v = f2m[j0 + t] - fmx;
      B1h[t] = (_Float16)__builtin_amdgcn_exp2f(v);
      B2h[t] = (_Float16)__builtin_amdgcn_exp2f(kAlpha * v);
    }
    __syncthreads();
    unsigned long long w0 = prow[(j0 >> 6)];
    unsigned long long w1 = prow[(j0 >> 6) + 1];
    #pragma unroll
    for (int ks = 0; ks < 4; ks++){
      unsigned long long wsel = (ks < 2) ? w0 : w1;
      unsigned int bits = (unsigned int)((wsel >> ((ks & 1) * 32 + q * 8)) & 0xffull);
      union { uint4 v; unsigned int u[4]; } b1v, b2v;
      b1v.v = *(const uint4*)&B1h[ks * 32 + q * 8];
      b2v.v = *(const uint4*)&B2h[ks * 32 + q * 8];
      union { half8 s; unsigned int u[4]; } af;
      #pragma unroll
      for (int e = 0; e < 4; e++){
        half2t x1 = __builtin_bit_cast(half2t, b1v.u[e]);
        half2t x2 = __builtin_bit_cast(half2t, b2v.u[e]);
        half2t m1 = x1 * a1p;
        half2t m2 = x2 * a2p;
        half2t pm = __builtin_elementwise_max(m1, m2);
        unsigned int mm = (((bits >> (2 * e)) & 1u) ? 0x0000FFFFu : 0u)
                        | (((bits >> (2 * e + 1)) & 1u) ? 0xFFFF0000u : 0u);
        af.u[e] = __builtin_bit_cast(unsigned int, pm) & mm;
      }
      #pragma unroll
      for (int nt = 0; nt < 5; nt++){
        const half8 bf = *(const half8*)&HtL[(nt * 16 + n) * 136 + ks * 32 + q * 8];
        acc[nt] = __builtin_amdgcn_mfma_f32_16x16x32_f16(af.s, bf, acc[nt], 0, 0, 0);
      }
    }
  }
  _Float16* pw = paccb + ((size_t)(m * JSPLIT + js) * kN + (i0 + w * 16)) * 72;
  #pragma unroll
  for (int nt = 0; nt < 5; nt++){
    if (nt < 4 || n < 4){ // cols >= 68 unused
      #pragma unroll
      for (int r = 0; r < 4; r++)
        pw[(q * 4 + r) * 72 + nt * 16 + n] = (_Float16)acc[nt][r];
    }
  }
}

// ---------- fused: combine 4-head/4-split partials -> LDS hcat -> out GEMM (K=288) -> epi0 ----------
__global__ __launch_bounds__(256) void combineH_gemmO_k(
    const _Float16* __restrict__ pacc, const _Float16* __restrict__ B2tc,
    _Float16* __restrict__ Htoc, float* __restrict__ fo1c, float* __restrict__ fo2c,
    unsigned int* __restrict__ fmaxslot)
{
  __shared__ __align__(16) _Float16 hcatL[64 * 296];
  const int t = threadIdx.x;
  const int i0 = blockIdx.x * 64;
  {
    const int mm = t >> 6, row = t & 63;
    const _Float16* pb = pacc + ((size_t)(mm * 4) * kN + (i0 + row)) * 72;
    constexpr size_t jstep = (size_t)kN * 72;
    float l = 0.f;
    #pragma unroll
    for (int s = 0; s < 4; s++) l += (float)pb[s * jstep + 66];
    float inv = 1.f / l;
    _Float16* hr = hcatL + row * 296 + mm * 66;
    #pragma unroll
    for (int c8 = 0; c8 < 9; c8++){
      float sv[8] = {0.f,0.f,0.f,0.f,0.f,0.f,0.f,0.f};
      #pragma unroll
      for (int s = 0; s < 4; s++){
        half8 hv = *(const half8*)&pb[s * jstep + c8 * 8];
        #pragma unroll
        for (int e = 0; e < 8; e++) sv[e] += (float)hv[e];
      }
      #pragma unroll
      for (int e = 0; e < 8; e++){
        int c = c8 * 8 + e;
        if (c < kDim){
          float vv = sv[e] * inv;
          vv = fmaxf(vv, kSlope * vv);
          hr[c] = (_Float16)vv;
        }
      }
    }
  }
  for (int z = t; z < 64 * 32; z += 256)
    hcatL[(z >> 5) * 296 + 264 + (z & 31)] = (_Float16)0.f;
  __syncthreads();
  const int w = t >> 6, n = t & 15;
  floatx4 acc[5];
  gemmN<9, 5>(hcatL + (w * 16 + n) * 296, B2tc, acc);
  epi0(acc, i0, Htoc, fo1c, fo2c, fmaxslot);
}

// ---------- fused: combine 16 out-split partials -> LDS -> gate(EPI=1)/final(EPI=2) GEMM ----------
template<int EPI>
__global__ __launch_bounds__(256) void combineO_gemm_k(
    const _Float16* __restrict__ pacc, const _Float16* __restrict__ Btc,
    float* __restrict__ uv, const float* __restrict__ hxp,
    _Float16* __restrict__ x2bp, float* __restrict__ outp)
{
  __shared__ __align__(16) _Float16 gbL[64 * 104];
  const int t = threadIdx.x;
  const int i0 = blockIdx.x * 64;
  {
    const int row = t >> 2, cg = t & 3;
    const _Float16* pb = pacc + (size_t)(i0 + row) * 72;
    constexpr size_t jstep = (size_t)kN * 72;
    float l = 0.f;
    #pragma unroll
    for (int s = 0; s < 16; s++) l += (float)pb[s * jstep + 66];
    float inv = 1.f / l;
    _Float16* gr = gbL + row * 104;
    for (int cc = 0; cc < 17; cc++){
      int c = cg * 17 + cc;
      if (c < kDim){
        float vv = 0.f;
        #pragma unroll
        for (int s = 0; s < 16; s++) vv += (float)pb[s * jstep + c];
        vv *= inv; vv = fmaxf(vv, kSlope * vv);
        gr[c] = (_Float16)vv;
      } else if (c == 66) gr[66] = (_Float16)1.f;
      else if (c == 67) gr[67] = (_Float16)0.f;
    }
    #pragma unroll
    for (int e = 0; e < 9; e++) gr[68 + cg * 9 + e] = (_Float16)0.f;
  }
  __syncthreads();
  const int w = t >> 6, lane = t & 63, q = lane >> 4, n = lane & 15;
  const int ib = i0 + w * 16 + q * 4;
  if constexpr (EPI == 1){
    floatx4 acc[8];
    gemmN<3, 8>(gbL + (w * 16 + n) * 104, Btc, acc);
    #pragma unroll
    for (int nt = 0; nt < 8; nt++){
      int c = nt * 16 + n;
      #pragma unroll
      for (int r = 0; r < 4; r++){
        float v = 1.f / (1.f + __expf(-acc[nt][r]));
        if (c < 64) x2bp[(size_t)(ib + r) * 96 + 2 + c] = (_Float16)(v * hxp[(size_t)(ib + r) * kU + c]);
        else        uv[(size_t)(ib + r) * kU + (c - 64)] = v;
      }
    }
  } else {
    floatx4 acc[4];
    gemmN<3, 4>(gbL + (w * 16 + n) * 104, Btc, acc);
    #pragma unroll
    for (int nt = 0; nt < 4; nt++){
      int c = nt * 16 + n;
      #pragma unroll
      for (int r = 0; r < 4; r++){
        float cc2 = tanhf(acc[nt][r]);
        float u2 = uv[(size_t)(ib + r) * kU + c];
        outp[(size_t)(ib + r) * kU + c] = u2 * hxp[(size_t)(ib + r) * kU + c] + (1.f - u2) * cc2;
      }
    }
  }
}

extern "C" void kernel_launch(void* const* d_in, const int* in_sizes, int n_in,
                              void* d_out, int out_size, void* d_ws, size_t ws_size,
                              hipStream_t stream){
  const float* inputs  = (const float*)d_in[0];
  const float* hx      = (const float*)d_in[1];
  const int*   adj     = (const int*)d_in[2];
  const float* m1_W    = (const float*)d_in[3];
  const float* m1_a1   = (const float*)d_in[4];
  const float* m1_a2   = (const float*)d_in[5];
  const float* m1_Wout = (const float*)d_in[6];
  const float* m1_ao1  = (const float*)d_in[7];
  const float* m1_ao2  = (const float*)d_in[8];
  const float* m2_W    = (const float*)d_in[9];
  const float* m2_a1   = (const float*)d_in[10];
  const float* m2_a2   = (const float*)d_in[11];
  const float* m2_Wout = (const float*)d_in[12];
  const float* m2_ao1  = (const float*)d_in[13];
  const float* m2_ao2  = (const float*)d_in[14];
  const float* g1_W    = (const float*)d_in[15];
  const float* g1_b    = (const float*)d_in[16];
  const float* g2_W    = (const float*)d_in[17];
  const float* g2_b    = (const float*)d_in[18];
  float* out = (float*)d_out;

  char* ws = (char*)d_ws;
  size_t off = 0;
  auto alloc = [&](size_t bytes) -> void* {
    void* p = ws + off;
    off = (off + bytes + 255) & ~(size_t)255;
    return p;
  };
  unsigned long long* packed = (unsigned long long*)alloc((size_t)kN * 64 * 8);
  _Float16* x1b  = (_Float16*)alloc((size_t)kN * 96 * 2);
  _Float16* x2b  = (_Float16*)alloc((size_t)kN * 96 * 2);
  _Float16* Ht   = (_Float16*)alloc((size_t)4 * 68 * kN * 2);
  _Float16* Hto  = (_Float16*)alloc((size_t)68 * kN * 2);
  float* f1   = (float*)alloc((size_t)4 * kN * 4);
  float* f2   = (float*)alloc((size_t)4 * kN * 4);
  float* fo1  = (float*)alloc((size_t)kN * 4);
  float* fo2  = (float*)alloc((size_t)kN * 4);
  unsigned int* fmaxbuf = (unsigned int*)alloc(64);
  float* u    = (float*)alloc((size_t)kN * kU * 4);
  _Float16* pacc = (_Float16*)alloc((size_t)16 * kN * 72 * 2);
  _Float16* B1t  = (_Float16*)alloc((size_t)4 * 80 * 96 * 2);
  _Float16* B1t2 = (_Float16*)alloc((size_t)4 * 80 * 96 * 2);
  _Float16* B2t  = (_Float16*)alloc((size_t)80 * 288 * 2);
  _Float16* B2t2 = (_Float16*)alloc((size_t)80 * 288 * 2);
  _Float16* Bgt  = (_Float16*)alloc((size_t)128 * 96 * 2);
  _Float16* Bft  = (_Float16*)alloc((size_t)64 * 96 * 2);
  (void)ws_size; (void)in_sizes; (void)n_in; (void)out_size;

  setup_k<<<16384 + 1024 + 12, 256, 0, stream>>>(adj, packed, inputs, hx, x1b, x2b,
      m1_W, m1_a1, m1_a2, m1_Wout, m1_ao1, m1_ao2,
      m2_W, m2_a1, m2_a2, m2_Wout, m2_ao1, m2_ao2,
      g1_W, g1_b, g2_W, g2_b,
      B1t, B1t2, B2t, B2t2, Bgt, Bft, fmaxbuf);

  // ---- subnet 1 ----
  gemm_ht_k<<<dim3(64, 4), 256, 0, stream>>>(x1b, B1t, Ht, f1, f2, fmaxbuf + 0);
  attn_mfma_k<4><<<dim3(64, 4, 4), 256, 0, stream>>>(Ht, f1, f2, fmaxbuf + 0, packed, pacc);
  combineH_gemmO_k<<<64, 256, 0, stream>>>(pacc, B2t, Hto, fo1, fo2, fmaxbuf + 4);
  attn_mfma_k<16><<<dim3(64, 1, 16), 256, 0, stream>>>(Hto, fo1, fo2, fmaxbuf + 4, packed, pacc);
  combineO_gemm_k<1><<<64, 256, 0, stream>>>(pacc, Bgt, u, hx, x2b, nullptr);

  // ---- subnet 2 ----
  gemm_ht_k<<<dim3(64, 4), 256, 0, stream>>>(x2b, B1t2, Ht, f1, f2, fmaxbuf + 5);
  attn_mfma_k<4><<<dim3(64, 4, 4), 256, 0, stream>>>(Ht, f1, f2, fmaxbuf + 5, packed, pacc);
  combineH_gemmO_k<<<64, 256, 0, stream>>>(pacc, B2t2, Hto, fo1, fo2, fmaxbuf + 9);
  attn_mfma_k<16><<<dim3(64, 1, 16), 256, 0, stream>>>(Hto, fo1, fo2, fmaxbuf + 9, packed, pacc);
  combineO_gemm_k<2><<<64, 256, 0, stream>>>(pacc, Bft, u, hx, nullptr, out);
}